// Round 14
// baseline (63.663 us; speedup 1.0000x reference)
//
#include <hip/hip_runtime.h>
#include <hip/hip_fp16.h>

// ROIAlign: input (B=2, C=256, H=200, W=200) f32, rois (R=512, 5) f32
// output (R, C, 7, 7) f32.  sampling_ratio = 2, spatial_scale = 0.0625.
//
// Round 14: eliminate the LDS-DMA round trip (vmcnt serialization + lgkm
// drains + 5.8M bank-conflict cycles). Direct-gather compute (r2 structure)
// + r10's XCD-spatial sort (corner loads hit L2, FETCH ~60MB) + meta tables
// (geometry VALU ~0). One wave per (roi, cgroup), 8 channels, 2-deep channel
// pipeline, no LDS at all.

#define B_  2
#define C_  256
#define H_  200
#define W_  200
#define R_  512
#define HW_ (H_ * W_)
#define G_   8      // channels per wave

#define HDR_BYTES_  (R_ * 8 * 4)              // 16384
#define META_BYTES_ (R_ * 4 * 64 * 16)        // 2097152
#define PERM_BYTES_ (R_ * 4)                  // 2048
#define WS_NEED_    (HDR_BYTES_ + META_BYTES_ + PERM_BYTES_)

typedef __attribute__((address_space(3))) unsigned int lds_u32;
typedef const __attribute__((address_space(1))) unsigned int glb_u32;

__device__ __forceinline__ float sample_coord(float start, float bin, int p, int i) {
    // Single definition shared by bounds and per-sample math.
    return start + (float)p * bin + ((float)i + 0.5f) * bin * 0.5f;
}
__device__ __forceinline__ int lo_clamped(float v, int size) {
    return (int)fminf(floorf(fmaxf(v, 0.0f)), (float)(size - 1));
}
__device__ __forceinline__ unsigned int pack_h2(float a, float b) {
    unsigned short ua = __half_as_ushort(__float2half(a));
    unsigned short ub = __half_as_ushort(__float2half(b));
    return (unsigned int)ua | ((unsigned int)ub << 16);
}
__device__ __forceinline__ float h2f_lo(unsigned int u) {
    return __half2float(__ushort_as_half((unsigned short)(u & 0xffffu)));
}
__device__ __forceinline__ float h2f_hi(unsigned int u) {
    return __half2float(__ushort_as_half((unsigned short)(u >> 16)));
}

// ------- sort kernel: counting-rank (O(n^2), 1 barrier) -------
// key = (image<<10) | (y_stripe<<8) | x_quant; tie-broken by idx -> unique.
// perm[rank(t)] = t gives 8 spatially-compact chunks of 64 rois.
__global__ __launch_bounds__(512) void roialign_sort(
    const float* __restrict__ rois, int* __restrict__ perm) {
    __shared__ unsigned int keys[R_];
    int t = threadIdx.x;

    float bf = rois[t * 5 + 0];
    float cx = (rois[t * 5 + 1] + rois[t * 5 + 3]) * 0.5f * 0.0625f;
    float cy = (rois[t * 5 + 2] + rois[t * 5 + 4]) * 0.5f * 0.0625f;
    int bi = (int)bf;
    int ys = min(3, max(0, (int)(cy * (4.0f / 200.0f))));
    int xq = min(255, max(0, (int)(cx * (256.0f / 200.0f))));
    unsigned int key = ((unsigned int)bi << 10) | ((unsigned int)ys << 8) |
                       (unsigned int)xq;
    unsigned int mykey = (key << 9) | (unsigned int)t;
    keys[t] = mykey;
    __syncthreads();

    int rank = 0;
#pragma unroll 8
    for (int u = 0; u < R_; ++u)
        rank += (keys[u] < mykey) ? 1 : 0;   // broadcast read, conflict-free
    perm[rank] = t;
}

// ---------------- meta kernel: one 64-thread block per roi ----------------
// Per (output-lane, sample) gather entry: {base2, dyW|sx<<30, wy01, wx01}.
// base2 = ylo*W + min(xlo, W-2): float2 at base2 covers {xlo, xlo+1} (or the
// sx edge pair {W-2, W-1}); second row at +dyW. Weights: mask*0.25 folded
// into wy. Lanes >= 49 emit zeros -> loads of plane[0..1], weight 0: safe.
__global__ __launch_bounds__(64) void roialign_meta(
    const float* __restrict__ rois, int* __restrict__ hdr, int4* __restrict__ meta) {
    int r = blockIdx.x;
    int lane = threadIdx.x;

    const float scale = 0.0625f;
    float bf = rois[r * 5 + 0];
    int   bi = (int)bf;
    float x1 = rois[r * 5 + 1] * scale;
    float y1 = rois[r * 5 + 2] * scale;
    float x2 = rois[r * 5 + 3] * scale;
    float y2 = rois[r * 5 + 4] * scale;
    float bin_w = fmaxf(x2 - x1, 1.0f) * (1.0f / 7.0f);
    float bin_h = fmaxf(y2 - y1, 1.0f) * (1.0f / 7.0f);

    if (lane == 0) {
        int* h = hdr + r * 8;
        h[1] = bi;
    }

    int4 o[4] = {{0,0,0,0},{0,0,0,0},{0,0,0,0},{0,0,0,0}};
    if (lane < 49) {
        int ph = lane / 7;
        int pw = lane % 7;

        int   ylo[2], dyW[2];
        float fy[2];
        bool  vy[2];
#pragma unroll
        for (int iy = 0; iy < 2; ++iy) {
            float y = sample_coord(y1, bin_h, ph, iy);
            vy[iy] = (y >= -1.0f) && (y <= (float)H_);
            float yc = fmaxf(y, 0.0f);
            float yl = floorf(yc);
            bool  edge = yl >= (float)(H_ - 1);
            int   lo = (int)fminf(yl, (float)(H_ - 1));
            int   hi = min(lo + 1, H_ - 1);
            fy[iy] = edge ? 0.0f : (yc - yl);
            ylo[iy] = lo;
            dyW[iy] = (hi - lo) * W_;     // 0 or W_
        }
        int   xo[2];
        bool  sx[2];
        float fx[2];
        bool  vx[2];
#pragma unroll
        for (int ix = 0; ix < 2; ++ix) {
            float x = sample_coord(x1, bin_w, pw, ix);
            vx[ix] = (x >= -1.0f) && (x <= (float)W_);
            float xc = fmaxf(x, 0.0f);
            float xl = floorf(xc);
            bool  edge = xl >= (float)(W_ - 1);
            int   lo = (int)fminf(xl, (float)(W_ - 1));
            fx[ix] = edge ? 0.0f : (xc - xl);
            sx[ix] = (lo == W_ - 1);
            xo[ix] = min(lo, W_ - 2);
        }
#pragma unroll
        for (int iy = 0; iy < 2; ++iy)
#pragma unroll
            for (int ix = 0; ix < 2; ++ix) {
                int s = iy * 2 + ix;
                float mk  = (vy[iy] && vx[ix]) ? 0.25f : 0.0f;  // mask * 1/(S*S)
                float wy0 = (1.0f - fy[iy]) * mk;
                float wy1 = fy[iy] * mk;
                float wx0 = 1.0f - fx[ix];
                float wx1 = fx[ix];
                o[s].x = ylo[iy] * W_ + xo[ix];
                o[s].y = dyW[iy] | (sx[ix] ? (1 << 30) : 0);
                o[s].z = (int)pack_h2(wy0, wy1);
                o[s].w = (int)pack_h2(wx0, wx1);
            }
    }
#pragma unroll
    for (int s = 0; s < 4; ++s)
        meta[((r * 4 + s) * 64) + lane] = o[s];
}

// ---------------- direct-gather main kernel ----------------
__device__ __forceinline__ void load_ch(
    const float* __restrict__ plane, const int4 (&m)[4], float2 (&d)[8]) {
#pragma unroll
    for (int s = 0; s < 4; ++s) {
        int base2 = m[s].x;
        int dyW   = m[s].y & 0xffff;
        d[s * 2 + 0] = *(const float2*)(plane + base2);
        d[s * 2 + 1] = *(const float2*)(plane + base2 + dyW);
    }
}

__device__ __forceinline__ float compute_ch(
    const float2 (&d)[8], const int4 (&m)[4], const float (&wt)[16]) {
    float a = 0.0f;
#pragma unroll
    for (int s = 0; s < 4; ++s) {
        bool sx = (m[s].y >> 30) & 1;
        float2 A = d[s * 2 + 0];
        float2 Bv = d[s * 2 + 1];
        float v1 = sx ? A.y : A.x;
        float v3 = sx ? Bv.y : Bv.x;
        a += wt[4*s+0] * (wt[4*s+2] * v1 + wt[4*s+3] * A.y)
           + wt[4*s+1] * (wt[4*s+2] * v3 + wt[4*s+3] * Bv.y);
    }
    return a;
}

__global__ __launch_bounds__(256) void roialign_gather(
    const float* __restrict__ input, const int* __restrict__ hdr,
    const int4* __restrict__ meta, const int* __restrict__ perm,
    float* __restrict__ out) {
    int tid  = threadIdx.x;
    int lane = tid & 63;
    int w    = tid >> 6;          // wave 0..3 (independent; no LDS, no barriers)
    int bidx = blockIdx.x;

    // XCD-spatial mapping (r10): xcd = bidx&7; XCD x owns the 64 clustered
    // rois perm[x*64..x*64+63]; roi varies fastest, block-group next.
    // Block = 4 waves = 4 consecutive cgroups of one roi.
    int xcd  = bidx & 7;
    int ixn  = bidx >> 3;                 // 0..511
    int rank = (xcd << 6) | (ixn & 63);
    int bg   = ixn >> 6;                  // 0..7
    int r    = perm[rank];                // uniform load
    int cg   = (bg << 2) | w;             // 0..31
    int c0   = cg << 3;

    // Meta loads (long latency, independent).
    int4 m[4];
#pragma unroll
    for (int s = 0; s < 4; ++s)
        m[s] = meta[(((r << 2) + s) << 6) + lane];

    int bi = hdr[(r << 3) + 1];           // uniform

    float wt[16];
#pragma unroll
    for (int s = 0; s < 4; ++s) {
        unsigned int d2 = (unsigned int)m[s].z;
        unsigned int d3 = (unsigned int)m[s].w;
        wt[4*s+0] = h2f_lo(d2);
        wt[4*s+1] = h2f_hi(d2);
        wt[4*s+2] = h2f_lo(d3);
        wt[4*s+3] = h2f_hi(d3);
    }

    const float* plane0 = input + ((size_t)bi * C_ + c0) * HW_;
    int obase = (r * C_ + c0) * 49 + lane;

    // 2-deep channel pipeline: load ch k+1 while computing ch k.
    float2 dA[8], dB[8];
    float accs[G_];
    load_ch(plane0, m, dA);
#pragma unroll
    for (int k = 0; k < G_; ++k) {
        if (k + 1 < G_)
            load_ch(plane0 + (k + 1) * HW_, m, (k & 1) ? dA : dB);
        accs[k] = compute_ch((k & 1) ? dB : dA, m, wt);
    }

    if (lane < 49) {
#pragma unroll
        for (int k = 0; k < G_; ++k)
            out[obase + k * 49] = accs[k];
    }
}

// ---------------- fallback (round-4 kernel, used if ws too small) ----------
#define RMAX_   41
#define STRIDE_ 42

__global__ __launch_bounds__(128) void roialign_fallback(
    const float* __restrict__ input,
    const float* __restrict__ rois,
    float* __restrict__ out) {
    __shared__ float lds[2][RMAX_ * STRIDE_];

    int lane = threadIdx.x & 63;
    int wv   = threadIdx.x >> 6;
    int bidx = blockIdx.x;
    int r = bidx >> 7;
    int c = ((bidx & 127) << 1) | wv;

    const float scale = 0.0625f;
    float bf = rois[r * 5 + 0];
    int   bi = (int)bf;
    float x1 = rois[r * 5 + 1] * scale;
    float y1 = rois[r * 5 + 2] * scale;
    float x2 = rois[r * 5 + 3] * scale;
    float y2 = rois[r * 5 + 4] * scale;
    float bin_w = fmaxf(x2 - x1, 1.0f) * (1.0f / 7.0f);
    float bin_h = fmaxf(y2 - y1, 1.0f) * (1.0f / 7.0f);

    int y0 = lo_clamped(sample_coord(y1, bin_h, 0, 0), H_);
    int x0 = lo_clamped(sample_coord(x1, bin_w, 0, 0), W_);
    int yE = min(lo_clamped(sample_coord(y1, bin_h, 6, 1), H_) + 1, H_ - 1);
    int xE = min(lo_clamped(sample_coord(x1, bin_w, 6, 1), W_) + 1, W_ - 1);
    int rows = min(yE - y0 + 1, RMAX_);
    int cols = min(xE - x0 + 1, RMAX_);

    const float* plane = input + ((size_t)bi * C_ + c) * HW_;
    float* myl = lds[wv];
    for (int rr = 0; rr < rows; ++rr) {
        lds_u32* dst = (lds_u32*)(myl + rr * STRIDE_);
        const float* src = plane + (y0 + rr) * W_ + x0 + lane;
        if (lane < cols)
            __builtin_amdgcn_global_load_lds((glb_u32*)src, dst, 4, 0, 0);
    }
    asm volatile("s_waitcnt vmcnt(0)" ::: "memory");
    __builtin_amdgcn_sched_barrier(0);

    if (lane < 49) {
        int ph = lane / 7;
        int pw = lane % 7;
        int   ry[2][2];
        float fy[2];
        bool  vy[2];
#pragma unroll
        for (int iy = 0; iy < 2; ++iy) {
            float y = sample_coord(y1, bin_h, ph, iy);
            vy[iy] = (y >= -1.0f) && (y <= (float)H_);
            float yc = fmaxf(y, 0.0f);
            float yl = floorf(yc);
            bool  edge = yl >= (float)(H_ - 1);
            int   lo = (int)fminf(yl, (float)(H_ - 1));
            int   hi = min(lo + 1, H_ - 1);
            fy[iy] = edge ? 0.0f : (yc - yl);
            ry[iy][0] = (lo - y0) * STRIDE_;
            ry[iy][1] = (hi - y0) * STRIDE_;
        }
        int   rxl[2], rxh[2];
        float fx[2];
        bool  vx[2];
#pragma unroll
        for (int ix = 0; ix < 2; ++ix) {
            float x = sample_coord(x1, bin_w, pw, ix);
            vx[ix] = (x >= -1.0f) && (x <= (float)W_);
            float xc = fmaxf(x, 0.0f);
            float xl = floorf(xc);
            bool  edge = xl >= (float)(W_ - 1);
            int   lo = (int)fminf(xl, (float)(W_ - 1));
            int   hi = min(lo + 1, W_ - 1);
            fx[ix] = edge ? 0.0f : (xc - xl);
            rxl[ix] = lo - x0;
            rxh[ix] = hi - x0;
        }
        float acc = 0.0f;
#pragma unroll
        for (int iy = 0; iy < 2; ++iy) {
            float lyw = fy[iy], hyw = 1.0f - lyw;
#pragma unroll
            for (int ix = 0; ix < 2; ++ix) {
                float lxw = fx[ix], hxw = 1.0f - lxw;
                float msk = (vy[iy] && vx[ix]) ? 1.0f : 0.0f;
                float v1 = myl[ry[iy][0] + rxl[ix]];
                float v2 = myl[ry[iy][0] + rxh[ix]];
                float v3 = myl[ry[iy][1] + rxl[ix]];
                float v4 = myl[ry[iy][1] + rxh[ix]];
                acc += msk * (hyw * hxw * v1 + hyw * lxw * v2 +
                              lyw * hxw * v3 + lyw * lxw * v4);
            }
        }
        out[(r * C_ + c) * 49 + lane] = acc * 0.25f;
    }
}

extern "C" void kernel_launch(void* const* d_in, const int* in_sizes, int n_in,
                              void* d_out, int out_size, void* d_ws, size_t ws_size,
                              hipStream_t stream) {
    const float* input = (const float*)d_in[0];
    const float* rois  = (const float*)d_in[1];
    float* out = (float*)d_out;

    if (ws_size >= (size_t)WS_NEED_) {
        int*  hdr  = (int*)d_ws;
        int4* meta = (int4*)((char*)d_ws + HDR_BYTES_);
        int*  perm = (int*)((char*)d_ws + HDR_BYTES_ + META_BYTES_);
        roialign_sort<<<1, R_, 0, stream>>>(rois, perm);
        roialign_meta<<<R_, 64, 0, stream>>>(rois, hdr, meta);
        // 4096 blocks x 4 waves: 512 rois x 8 block-groups (4 cgroups each).
        roialign_gather<<<R_ * 8, 256, 0, stream>>>(input, hdr, meta, perm, out);
    } else {
        roialign_fallback<<<R_ * (C_ / 2), 128, 0, stream>>>(input, rois, out);
    }
}